// Round 6
// baseline (277.705 us; speedup 1.0000x reference)
//
#include <hip/hip_runtime.h>
#include <math.h>

// Problem constants (from reference setup_inputs).
constexpr int B_ = 2048;
constexpr int C_ = 9605;
constexpr int L_ = 8;
constexpr int TOPK_ = 16;
constexpr int CAP_ = 128;       // LDS candidate capacity (expected ~69/row @ T0=2.45)
constexpr float T0_ = 2.45f;    // candidate prefilter (16th largest ~2.93; P(cnt<16)~1e-15, P(cnt>128)~1e-12)
constexpr int GSEG_ = 512;      // padded per-group index segment (members ~248+-16)

typedef float vfloat4 __attribute__((ext_vector_type(4)));

__device__ __forceinline__ float sigm(float v) { return 1.0f / (1.0f + expf(-v)); }

// our_rank_loss: d = x2 - x1 + margin; s = sigmoid(5d); 2s when violated (d>0)
__device__ __forceinline__ float rank_loss(float x1, float x2) {
  float d = x2 - x1 + 0.05f;
  float s = 1.0f / (1.0f + expf(-5.0f * d));
  return (d > 0.0f) ? 2.0f * s : s;
}

// Order-preserving float->uint key (ascending) and inverse.
__device__ __forceinline__ unsigned int fkey(float v) {
  unsigned int u = __float_as_uint(v);
  return u ^ ((u & 0x80000000u) ? 0xFFFFFFFFu : 0x80000000u);
}
__device__ __forceinline__ float fkeyinv(unsigned int k) {
  unsigned int u = (k & 0x80000000u) ? (k ^ 0x80000000u) : ~k;
  return __uint_as_float(u);
}

// Kernel 0a: group_mask [L, C] int32 (bool promoted) -> per-class code byte.
__global__ void build_code_kernel(const int* __restrict__ mask,
                                  unsigned char* __restrict__ code) {
  int c = blockIdx.x * 256 + threadIdx.x;
  if (c >= C_) return;
  unsigned char cd = 0xFF;
#pragma unroll
  for (int l = L_ - 1; l >= 0; --l)
    if (mask[l * C_ + c] != 0) cd = (unsigned char)l;
  code[c] = cd;
}

// Kernel 0b: per-group padded index lists (pad with a repeated member).
__global__ void build_glist_kernel(const unsigned char* __restrict__ code,
                                   unsigned int* __restrict__ glist) {
  __shared__ int cnt;
  __shared__ unsigned int firstidx;
  const int l = blockIdx.x;
  const int t = threadIdx.x;
  if (t == 0) { cnt = 0; firstidx = 0u; }
  __syncthreads();
  for (int c = t; c < C_; c += 256) {
    if (code[c] == (unsigned char)l) {
      int p = atomicAdd(&cnt, 1);
      if (p < GSEG_) glist[l * GSEG_ + p] = (unsigned int)c;
      if (p == 0) firstidx = (unsigned int)c;
    }
  }
  __syncthreads();
  int n = (cnt < GSEG_) ? cnt : GSEG_;
  unsigned int f = firstidx;
  for (int s = n + t; s < GSEG_; s += 256) glist[l * GSEG_ + s] = f;
}

// Kernel 1: one block per row, single fused pass, ALLOCATING loads, deep MLP:
// round A = 18 loads in flight (6 iters x 3 streams), round B = 12. Group max
// via glist gather; gt bits via rare-branch register OR; candidates via
// rare-branch LDS append; exact 16th-largest; per-block atomicAdd of loss/B.
__global__ void __launch_bounds__(256) row_loss_kernel(
    const float* __restrict__ x, const float* __restrict__ y,
    const float* __restrict__ yn, const unsigned char* __restrict__ code,
    const unsigned int* __restrict__ glist, float* __restrict__ out) {
  __shared__ float cand[CAP_];
  __shared__ int cand_cnt;
  __shared__ float wgm[4][L_];
  __shared__ unsigned int wgt[4], wgn[4];
  __shared__ float s_x16;
  __shared__ int s_red;

  const int t = threadIdx.x;
  const int b = blockIdx.x;
  const size_t rb = (size_t)b * C_;
  const float* xr = x + rb;
  const float* yr = y + rb;
  const float* nr = yn + rb;
  if (t == 0) cand_cnt = 0;
  __syncthreads();

  unsigned int gtb = 0u, gnb = 0u;

  auto cappend = [&](float v) {
    int p = atomicAdd(&cand_cnt, 1);
    if (p < CAP_) cand[p] = v;
  };
  auto candq = [&](vfloat4 v) {
    float m = fmaxf(fmaxf(v.x, v.y), fmaxf(v.z, v.w));
    if (m > T0_) {  // ~2.8% of quads
      if (v.x > T0_) cappend(v.x);
      if (v.y > T0_) cappend(v.y);
      if (v.z > T0_) cappend(v.z);
      if (v.w > T0_) cappend(v.w);
    }
  };
  auto posq = [&](vfloat4 v, int c0, unsigned int& bits) {
    float m = fmaxf(fmaxf(v.x, v.y), fmaxf(v.z, v.w));
    if (m > 0.0f) {  // ~0.6% of quads
      if (v.x > 0.0f) { unsigned char cd = code[c0];     if (cd < L_) bits |= 1u << cd; }
      if (v.y > 0.0f) { unsigned char cd = code[c0 + 1]; if (cd < L_) bits |= 1u << cd; }
      if (v.z > 0.0f) { unsigned char cd = code[c0 + 2]; if (cd < L_) bits |= 1u << cd; }
      if (v.w > 0.0f) { unsigned char cd = code[c0 + 3]; if (cd < L_) bits |= 1u << cd; }
    }
  };
  auto scalar_elem = [&](int c) {
    float v = xr[c];
    if (v > T0_) cappend(v);
    if (yr[c] > 0.0f) { unsigned char cd = code[c]; if (cd < L_) gtb |= 1u << cd; }
    if (nr[c] > 0.0f) { unsigned char cd = code[c]; if (cd < L_) gnb |= 1u << cd; }
  };

  // Interior: aligned float4 body. Row offset in first quad: (b*C)%4 = b%4.
  const int lead = (4 - (b & 3)) & 3;
  const int n4 = (C_ - lead) >> 2;   // 2400 or 2401
  const vfloat4* x4 = reinterpret_cast<const vfloat4*>(x) + ((rb + lead) >> 2);
  const vfloat4* y4 = reinterpret_cast<const vfloat4*>(y) + ((rb + lead) >> 2);
  const vfloat4* v4 = reinterpret_cast<const vfloat4*>(yn) + ((rb + lead) >> 2);

  // Round A: quads [0,1536), 6 iterations, 18 independent loads in flight.
  {
    vfloat4 xa[6], ya[6], na[6];
#pragma unroll
    for (int i = 0; i < 6; ++i) xa[i] = x4[t + 256 * i];
#pragma unroll
    for (int i = 0; i < 6; ++i) ya[i] = y4[t + 256 * i];
#pragma unroll
    for (int i = 0; i < 6; ++i) na[i] = v4[t + 256 * i];
#pragma unroll
    for (int i = 0; i < 6; ++i) {
      int k = t + 256 * i;
      candq(xa[i]);
      posq(ya[i], lead + 4 * k, gtb);
      posq(na[i], lead + 4 * k, gnb);
    }
  }
  // Round B: quads [1536, n4), 4 iterations (last partially active).
  {
    int kk[4];
    bool act[4];
#pragma unroll
    for (int i = 0; i < 4; ++i) {
      int k = t + 256 * (6 + i);
      act[i] = (k < n4);
      kk[i] = act[i] ? k : (n4 - 1);   // clamped safe address, result unused
    }
    vfloat4 xa[4], ya[4], na[4];
#pragma unroll
    for (int i = 0; i < 4; ++i) xa[i] = x4[kk[i]];
#pragma unroll
    for (int i = 0; i < 4; ++i) ya[i] = y4[kk[i]];
#pragma unroll
    for (int i = 0; i < 4; ++i) na[i] = v4[kk[i]];
#pragma unroll
    for (int i = 0; i < 4; ++i) {
      if (act[i]) {
        candq(xa[i]);
        posq(ya[i], lead + 4 * kk[i], gtb);
        posq(na[i], lead + 4 * kk[i], gnb);
      }
    }
  }
  // Head (classes [0,lead)) and tail scalars (classes [lead+4*n4, C)), <=7.
  if (t < lead) scalar_elem(t);
  const int ts = lead + (n4 << 2);
  if (t >= 64 && t < 64 + (C_ - ts)) scalar_elem(ts + (t - 64));

  // Group maxima via gather: thread t covers slots t and t+256 of each group
  // segment (row-local addresses, L2/L3-served).
  float gm[L_];
#pragma unroll
  for (int l = 0; l < L_; ++l) {
    unsigned int ia = glist[l * GSEG_ + t];
    unsigned int ib = glist[l * GSEG_ + 256 + t];
    gm[l] = fmaxf(xr[ia], xr[ib]);
  }

  // Wave-level reduction (width 64): max per group, OR of gt bits.
#pragma unroll
  for (int off = 32; off > 0; off >>= 1) {
#pragma unroll
    for (int l = 0; l < L_; ++l) gm[l] = fmaxf(gm[l], __shfl_xor(gm[l], off, 64));
    gtb |= (unsigned int)__shfl_xor((int)gtb, off, 64);
    gnb |= (unsigned int)__shfl_xor((int)gnb, off, 64);
  }
  if ((t & 63) == 0) {
    int w = t >> 6;
#pragma unroll
    for (int l = 0; l < L_; ++l) wgm[w][l] = gm[l];
    wgt[w] = gtb;
    wgn[w] = gnb;
  }
  __syncthreads();

  const int cnt = cand_cnt;
  const bool mainp = (cnt >= TOPK_) && (cnt <= CAP_);
  if (mainp) {
    if (t < 64) {  // wave 0: binary search on ordered keys, candidates in regs
      unsigned int ku[CAP_ / 64];
#pragma unroll
      for (int k = 0; k < CAP_ / 64; ++k) {
        int idx = t + (k << 6);
        ku[k] = (idx < cnt) ? fkey(cand[idx]) : 0u;
      }
      unsigned int lo = 0u, hi = 0xFFFFFFFFu;
      for (int it = 0; it < 32 && lo < hi; ++it) {
        unsigned int mid = lo + ((hi - lo) >> 1) + 1u;
        int c16 = 0;
#pragma unroll
        for (int k = 0; k < CAP_ / 64; ++k) c16 += (ku[k] >= mid) ? 1 : 0;
#pragma unroll
        for (int off = 32; off > 0; off >>= 1) c16 += __shfl_xor(c16, off, 64);
        if (c16 >= TOPK_) lo = mid; else hi = mid - 1u;
      }
      if (t == 0) s_x16 = fkeyinv(lo);
    }
  } else {
    // Fallback (statistically never): exact block-wide counting binary search
    // re-reading the row. Block-uniform control flow -> barriers safe.
    unsigned int lo = 0u, hi = 0xFFFFFFFFu;
    for (int it = 0; it < 32; ++it) {
      if (lo >= hi) break;
      unsigned int mid = lo + ((hi - lo) >> 1) + 1u;
      if (t == 0) s_red = 0;
      __syncthreads();
      int cl = 0;
      for (int c = t; c < C_; c += 256) cl += (fkey(xr[c]) >= mid) ? 1 : 0;
      atomicAdd(&s_red, cl);
      __syncthreads();
      int total = s_red;
      __syncthreads();
      if (total >= TOPK_) lo = mid; else hi = mid - 1u;
    }
    if (t == 0) s_x16 = fkeyinv(lo);
  }
  __syncthreads();

  // Epilogue: combine 4 wave partials; one global atomicAdd of loss_b / B.
  if (t == 0) {
    float thres = fmaxf(sigm(s_x16), 0.3f);
    unsigned int gtbf = wgt[0] | wgt[1] | wgt[2] | wgt[3];
    unsigned int gnbf = wgn[0] | wgn[1] | wgn[2] | wgn[3];
    float caseB = 0.0f, unio = -INFINITY, negmax = -INFINITY;
#pragma unroll
    for (int l = 0; l < L_; ++l) {
      float gx = fmaxf(fmaxf(wgm[0][l], wgm[1][l]), fmaxf(wgm[2][l], wgm[3][l]));
      float g = sigm(gx);
      unio = fmaxf(unio, g);
      caseB += ((gtbf >> l) & 1u) ? rank_loss(g, thres) : rank_loss(thres, g);
      if ((gnbf >> l) & 1u) negmax = fmaxf(negmax, g);
    }
    float negscore = (gnbf != 0u) ? negmax : 0.0f;
    float caseA = 0.5f * rank_loss(thres, unio) + 0.5f * rank_loss(thres, negscore);
    float lb = (gtbf != 0u) ? caseB : caseA;
    atomicAdd(out, lb * (1.0f / (float)B_));
  }
}

extern "C" void kernel_launch(void* const* d_in, const int* in_sizes, int n_in,
                              void* d_out, int out_size, void* d_ws, size_t ws_size,
                              hipStream_t stream) {
  const float* x = (const float*)d_in[0];
  const float* y = (const float*)d_in[1];
  const float* yn = (const float*)d_in[2];
  const int* mask = (const int*)d_in[3];  // bool promoted to int32 by harness

  char* ws = (char*)d_ws;
  unsigned char* code = (unsigned char*)ws;            // 9605 B -> pad 9632
  unsigned int* glist = (unsigned int*)(ws + 9632);    // L_*GSEG_*4 = 16 KB

  hipMemsetAsync(d_out, 0, sizeof(float), stream);     // accumulator base
  hipLaunchKernelGGL(build_code_kernel, dim3((C_ + 255) / 256), dim3(256), 0, stream,
                     mask, code);
  hipLaunchKernelGGL(build_glist_kernel, dim3(L_), dim3(256), 0, stream,
                     code, glist);
  hipLaunchKernelGGL(row_loss_kernel, dim3(B_), dim3(256), 0, stream,
                     x, y, yn, code, glist, (float*)d_out);
}

// Round 7
// 262.022 us; speedup vs baseline: 1.0599x; 1.0599x over previous
//
#include <hip/hip_runtime.h>
#include <math.h>

// Problem constants (from reference setup_inputs).
constexpr int B_ = 2048;
constexpr int C_ = 9605;
constexpr int L_ = 8;
constexpr int TOPK_ = 16;
constexpr int CAP_ = 512;       // LDS candidate capacity (expected ~219/row @ T0=2.0)
constexpr float T0_ = 2.0f;     // candidate prefilter threshold (16th largest ~2.93)
constexpr int QW_ = 2404;       // packed-code quads per rotation (>= max n4 + 1)
constexpr int NQ_ = (B_ * C_) / 4;  // 4,917,760 flat quads (exactly divisible)
constexpr int SCANB_ = 2048;    // scan chunks per target array

typedef float vfloat4 __attribute__((ext_vector_type(4)));

__device__ __forceinline__ float sigm(float v) { return 1.0f / (1.0f + expf(-v)); }

// our_rank_loss: d = x2 - x1 + margin; s = sigmoid(5d); 2s when violated (d>0)
__device__ __forceinline__ float rank_loss(float x1, float x2) {
  float d = x2 - x1 + 0.05f;
  float s = 1.0f / (1.0f + expf(-5.0f * d));
  return (d > 0.0f) ? 2.0f * s : s;
}

// Order-preserving float->uint key (ascending) and inverse.
__device__ __forceinline__ unsigned int fkey(float v) {
  unsigned int u = __float_as_uint(v);
  return u ^ ((u & 0x80000000u) ? 0xFFFFFFFFu : 0x80000000u);
}
__device__ __forceinline__ float fkeyinv(unsigned int k) {
  unsigned int u = (k & 0x80000000u) ? (k ^ 0x80000000u) : ~k;
  return __uint_as_float(u);
}

// Kernel 0a: group_mask [L, C] int32 (bool promoted) -> per-class code byte.
__global__ void build_code_kernel(const int* __restrict__ mask,
                                  unsigned char* __restrict__ code) {
  int c = blockIdx.x * 256 + threadIdx.x;
  if (c >= C_) return;
  unsigned char cd = 0xFF;
#pragma unroll
  for (int l = L_ - 1; l >= 0; --l)
    if (mask[l * C_ + c] != 0) cd = (unsigned char)l;
  code[c] = cd;
}

// Kernel 0b: rotated packed code tables (one aligned dword per row-quad).
__global__ void pack_code_kernel(const unsigned char* __restrict__ code,
                                 unsigned int* __restrict__ codeq) {
  int k = blockIdx.x * 256 + threadIdx.x;
  int r = blockIdx.y;
  if (k >= QW_) return;
  unsigned int v = 0u;
#pragma unroll
  for (int e = 0; e < 4; ++e) {
    int c = r + 4 * k + e;
    unsigned int byte = (c < C_) ? (unsigned int)code[c] : 0xFFu;
    v |= byte << (8 * e);
  }
  codeq[r * QW_ + k] = v;
}

// Main kernel: 6144 blocks, three interleaved roles so BW-bound scan waves and
// VALU-bound row waves co-schedule on every CU (m114: time ~ max, not sum).
//   role 0 (b%3==0): per-row x pass -> 8 group maxima + 16th-largest to ws
//   role 1 (b%3==1): flat scan chunk of y  -> atomicOr per-row gt bits
//   role 2 (b%3==2): flat scan chunk of yn -> atomicOr per-row gt_neg bits
__global__ void __launch_bounds__(256) fused_main_kernel(
    const float* __restrict__ x, const float* __restrict__ y,
    const float* __restrict__ yn, const unsigned char* __restrict__ code,
    const unsigned int* __restrict__ codeq,
    float* __restrict__ x16g, float* __restrict__ wgmg,
    unsigned int* __restrict__ gtb_g, unsigned int* __restrict__ gnb_g) {
  const int t = threadIdx.x;
  const int role = blockIdx.x % 3;
  const int sub = blockIdx.x / 3;

  if (role != 0) {
    // ---- scan role: pure-BW stream over y or yn (R4 structure, 60us std) ----
    const float* arr = (role == 1) ? y : yn;
    unsigned int* dst = (role == 1) ? gtb_g : gnb_g;
    const vfloat4* a4 = reinterpret_cast<const vfloat4*>(arr);
    const int S = SCANB_ * 256;
    int q = sub * 256 + t;

    auto rare = [&](float v, int idx) {
      if (v > 0.0f) {
        int row = idx / C_;               // constexpr divisor -> magic mul
        int col = idx - row * C_;
        unsigned char cd = code[col];
        if (cd < L_) atomicOr(&dst[row], 1u << cd);
      }
    };
    auto chk = [&](vfloat4 v, int qq) {
      float m = fmaxf(fmaxf(v.x, v.y), fmaxf(v.z, v.w));
      if (m > 0.0f) {
        int base = qq << 2;
        rare(v.x, base); rare(v.y, base + 1); rare(v.z, base + 2); rare(v.w, base + 3);
      }
    };
    for (; q + 3 * S < NQ_; q += 4 * S) {
      vfloat4 v0 = a4[q];
      vfloat4 v1 = a4[q + S];
      vfloat4 v2 = a4[q + 2 * S];
      vfloat4 v3 = a4[q + 3 * S];
      chk(v0, q); chk(v1, q + S); chk(v2, q + 2 * S); chk(v3, q + 3 * S);
    }
    for (; q < NQ_; q += S) chk(a4[q], q);
    return;
  }

  // ---- row role: x + packed codes only (R4 structure, 60us standalone) ----
  __shared__ float cand[CAP_];
  __shared__ int cand_cnt;
  __shared__ float wgm[4][L_];
  __shared__ float s_x16;
  __shared__ int s_red;

  const int b = sub;                     // row index
  const float* xr = x + (size_t)b * C_;
  if (t == 0) cand_cnt = 0;

  float gm[L_];
#pragma unroll
  for (int l = 0; l < L_; ++l) gm[l] = -INFINITY;

  auto cappend = [&](float xv) {         // call only under (xv > T0_)
    int p = atomicAdd(&cand_cnt, 1);
    if (p < CAP_) cand[p] = xv;
  };
  auto procq = [&](vfloat4 xv, unsigned int cd4) {
    int c0 = (int)(cd4 & 0xFF), c1 = (int)((cd4 >> 8) & 0xFF);
    int c2 = (int)((cd4 >> 16) & 0xFF), c3 = (int)((cd4 >> 24) & 0xFF);
#pragma unroll
    for (int l = 0; l < L_; ++l) {
      float vl = (c0 == l) ? xv.x : -INFINITY;
      vl = (c1 == l) ? fmaxf(vl, xv.y) : vl;
      vl = (c2 == l) ? fmaxf(vl, xv.z) : vl;
      vl = (c3 == l) ? fmaxf(vl, xv.w) : vl;
      gm[l] = fmaxf(gm[l], vl);
    }
    if (xv.x > T0_) cappend(xv.x);
    if (xv.y > T0_) cappend(xv.y);
    if (xv.z > T0_) cappend(xv.z);
    if (xv.w > T0_) cappend(xv.w);
  };

  // Interior: aligned float4 body. Row offset in first quad: (b*C)%4 = b%4.
  const int lead = (4 - (b & 3)) & 3;
  const int n4 = (C_ - lead) >> 2;       // 2400 or 2401
  const vfloat4* x4 = reinterpret_cast<const vfloat4*>(x) + (((size_t)b * C_ + lead) >> 2);
  const unsigned int* cq = codeq + lead * QW_;

  // Unroll-4 batches cover k < 2048 (n4 >= 2400, so both batches full).
  for (int kb = 0; kb < 2048; kb += 1024) {
    int k0 = kb + t, k1 = k0 + 256, k2 = k0 + 512, k3 = k0 + 768;
    vfloat4 a0 = x4[k0];
    vfloat4 a1 = x4[k1];
    vfloat4 a2 = x4[k2];
    vfloat4 a3 = x4[k3];
    unsigned int q0 = cq[k0], q1 = cq[k1], q2 = cq[k2], q3 = cq[k3];
    procq(a0, q0); procq(a1, q1); procq(a2, q2); procq(a3, q3);
  }
  // Tail quads [2048, n4).
  for (int k = 2048 + t; k < n4; k += 256) procq(x4[k], cq[k]);

  // Head (classes [0,lead)) and tail scalars (classes [lead+4*n4, C)), <=4.
  auto scalar_elem = [&](int c) {
    float v = xr[c];
    int cd = (int)code[c];
#pragma unroll
    for (int l = 0; l < L_; ++l)
      if (cd == l) gm[l] = fmaxf(gm[l], v);
    if (v > T0_) cappend(v);
  };
  if (t < lead) scalar_elem(t);
  const int ts = lead + (n4 << 2);
  if (t >= 64 && t < 64 + (C_ - ts)) scalar_elem(ts + (t - 64));

  // Wave-level max reduction (width 64).
#pragma unroll
  for (int off = 32; off > 0; off >>= 1) {
#pragma unroll
    for (int l = 0; l < L_; ++l) gm[l] = fmaxf(gm[l], __shfl_xor(gm[l], off, 64));
  }
  if ((t & 63) == 0) {
    int w = t >> 6;
#pragma unroll
    for (int l = 0; l < L_; ++l) wgm[w][l] = gm[l];
  }
  __syncthreads();

  const int cnt = cand_cnt;
  const bool mainp = (cnt >= TOPK_) && (cnt <= CAP_);
  if (mainp) {
    if (t < 64) {  // wave 0: binary search on ordered keys, candidates in regs
      unsigned int ku[CAP_ / 64];
#pragma unroll
      for (int k = 0; k < CAP_ / 64; ++k) {
        int idx = t + (k << 6);
        ku[k] = (idx < cnt) ? fkey(cand[idx]) : 0u;
      }
      unsigned int lo = 0u, hi = 0xFFFFFFFFu;
      for (int it = 0; it < 32 && lo < hi; ++it) {
        unsigned int mid = lo + ((hi - lo) >> 1) + 1u;
        int c16 = 0;
#pragma unroll
        for (int k = 0; k < CAP_ / 64; ++k) c16 += (ku[k] >= mid) ? 1 : 0;
#pragma unroll
        for (int off = 32; off > 0; off >>= 1) c16 += __shfl_xor(c16, off, 64);
        if (c16 >= TOPK_) lo = mid; else hi = mid - 1u;
      }
      if (t == 0) s_x16 = fkeyinv(lo);
    }
  } else {
    // Fallback (statistically never): exact block-wide counting binary search
    // re-reading the row. Block-uniform control flow -> barriers safe.
    unsigned int lo = 0u, hi = 0xFFFFFFFFu;
    for (int it = 0; it < 32; ++it) {
      if (lo >= hi) break;
      unsigned int mid = lo + ((hi - lo) >> 1) + 1u;
      if (t == 0) s_red = 0;
      __syncthreads();
      int cl = 0;
      for (int c = t; c < C_; c += 256) cl += (fkey(xr[c]) >= mid) ? 1 : 0;
      atomicAdd(&s_red, cl);
      __syncthreads();
      int total = s_red;
      __syncthreads();
      if (total >= TOPK_) lo = mid; else hi = mid - 1u;
    }
    if (t == 0) s_x16 = fkeyinv(lo);
  }
  __syncthreads();

  // Write per-row results: 16th-largest x and combined 8 group maxima.
  if (t == 0) x16g[b] = s_x16;
  if (t < L_) {
    float gx = fmaxf(fmaxf(wgm[0][t], wgm[1][t]), fmaxf(wgm[2][t], wgm[3][t]));
    wgmg[b * L_ + t] = gx;
  }
}

// Epilogue: one thread per row; loss; deterministic-enough block sum + atomic.
__global__ void __launch_bounds__(256) finish_kernel(
    const float* __restrict__ x16g, const float* __restrict__ wgmg,
    const unsigned int* __restrict__ gtb_g, const unsigned int* __restrict__ gnb_g,
    float* __restrict__ out) {
  const int t = threadIdx.x;
  const int r = blockIdx.x * 256 + t;
  float lb = 0.0f;
  if (r < B_) {
    float thres = fmaxf(sigm(x16g[r]), 0.3f);
    unsigned int gtbf = gtb_g[r];
    unsigned int gnbf = gnb_g[r];
    float caseB = 0.0f, unio = -INFINITY, negmax = -INFINITY;
#pragma unroll
    for (int l = 0; l < L_; ++l) {
      float g = sigm(wgmg[r * L_ + l]);
      unio = fmaxf(unio, g);
      caseB += ((gtbf >> l) & 1u) ? rank_loss(g, thres) : rank_loss(thres, g);
      if ((gnbf >> l) & 1u) negmax = fmaxf(negmax, g);
    }
    float negscore = (gnbf != 0u) ? negmax : 0.0f;
    float caseA = 0.5f * rank_loss(thres, unio) + 0.5f * rank_loss(thres, negscore);
    lb = (gtbf != 0u) ? caseB : caseA;
  }
  // Block reduction then one atomic per block.
#pragma unroll
  for (int off = 32; off > 0; off >>= 1) lb += __shfl_xor(lb, off, 64);
  __shared__ float part[4];
  if ((t & 63) == 0) part[t >> 6] = lb;
  __syncthreads();
  if (t == 0)
    atomicAdd(out, (part[0] + part[1] + part[2] + part[3]) * (1.0f / (float)B_));
}

extern "C" void kernel_launch(void* const* d_in, const int* in_sizes, int n_in,
                              void* d_out, int out_size, void* d_ws, size_t ws_size,
                              hipStream_t stream) {
  const float* x = (const float*)d_in[0];
  const float* y = (const float*)d_in[1];
  const float* yn = (const float*)d_in[2];
  const int* mask = (const int*)d_in[3];  // bool promoted to int32 by harness

  char* ws = (char*)d_ws;
  float* x16g = (float*)ws;                          // [0, 8K)
  float* wgmg = (float*)(ws + 8192);                 // [8K, 72K)  2048*8 floats
  unsigned int* gtb = (unsigned int*)(ws + 73728);   // [72K, 80K)
  unsigned int* gnb = (unsigned int*)(ws + 81920);   // [80K, 88K)
  unsigned char* code = (unsigned char*)(ws + 90112);          // 9605 B
  unsigned int* codeq = (unsigned int*)(ws + 90112 + 9632);    // 4*QW_*4 B

  hipMemsetAsync(d_out, 0, sizeof(float), stream);
  hipMemsetAsync(gtb, 0, B_ * sizeof(unsigned int), stream);
  hipMemsetAsync(gnb, 0, B_ * sizeof(unsigned int), stream);
  hipLaunchKernelGGL(build_code_kernel, dim3((C_ + 255) / 256), dim3(256), 0, stream,
                     mask, code);
  hipLaunchKernelGGL(pack_code_kernel, dim3((QW_ + 255) / 256, 4), dim3(256), 0, stream,
                     code, codeq);
  hipLaunchKernelGGL(fused_main_kernel, dim3(3 * B_), dim3(256), 0, stream,
                     x, y, yn, code, codeq, x16g, wgmg, gtb, gnb);
  hipLaunchKernelGGL(finish_kernel, dim3((B_ + 255) / 256), dim3(256), 0, stream,
                     x16g, wgmg, gtb, gnb, (float*)d_out);
}